// Round 1
// 278.639 us; speedup vs baseline: 1.1232x; 1.1232x over previous
//
#include <hip/hip_runtime.h>

typedef __attribute__((ext_vector_type(8))) short s16x8;
typedef __attribute__((ext_vector_type(4))) float f32x4;
typedef unsigned short u16;

#define B_SZ 2
#define SEQ 8192
#define KD 1024
#define HD 1024
#define RK 16
#define CH 256
#define NCH 64          // total chunks = B_SZ * SEQ/CH
static constexpr float LR_SC = 0.02f;     // TTT_LR * SCALING
static constexpr float SCALE_OUT = 2.0f;  // SCALING

// ---------- helpers ----------
__device__ __forceinline__ u16 f2b(float f) {
  union { float f; unsigned int u; } c; c.f = f;
  unsigned int u = c.u;
  unsigned int r = (u + 0x7fffu + ((u >> 16) & 1u)) >> 16;
  return (u16)r;
}
__device__ __forceinline__ float b2f(u16 v) {
  union { unsigned int u; float f; } c; c.u = ((unsigned int)v) << 16; return c.f;
}
__device__ __forceinline__ void async16(const u16* g, u16* l) {
  __builtin_amdgcn_global_load_lds((const __attribute__((address_space(1))) void*)g,
                                   (__attribute__((address_space(3))) void*)l, 16, 0, 0);
}

// ---------- fp32 -> bf16 convert: Wb, Wp, initB in one dispatch ----------
__global__ __launch_bounds__(256) void cvt_all(const float* __restrict__ Wb,
                                               const float* __restrict__ Wp,
                                               const float* __restrict__ initB,
                                               u16* __restrict__ Wbb,
                                               u16* __restrict__ Wpb,
                                               u16* __restrict__ iBb) {
  int bid = blockIdx.x;
  const float* src; u16* dst; int base;
  if (bid < 1024)      { src = Wb;    dst = Wbb; base = bid; }
  else if (bid < 2048) { src = Wp;    dst = Wpb; base = bid - 1024; }
  else                 { src = initB; dst = iBb; base = bid - 2048; }
  int i = (base * 256 + threadIdx.x) * 4;
  float4 v = *(const float4*)(src + i);
  ushort4 o; o.x = f2b(v.x); o.y = f2b(v.y); o.z = f2b(v.z); o.w = f2b(v.w);
  *(ushort4*)(dst + i) = o;
}

// ---------- WpAT partials: part[hseg][k][r] = sum_{h in seg} initA[h][r]*Wp[h][k] ----------
// 64 blocks (was 16) + unroll 8: latency-bound fix — 8-deep MLP, 4x block parallelism.
__global__ __launch_bounds__(256) void wpat_part(const float* __restrict__ initA,
                                                 const float* __restrict__ Wp,
                                                 float* __restrict__ part) {
  int t = threadIdx.x;
  int k = blockIdx.x * 256 + t;
  int hseg = blockIdx.y;               // 0..15, 64 h-rows each
  __shared__ float Asm[64 * 16];
  *(float4*)&Asm[t * 4] = *(const float4*)&initA[(size_t)hseg * 1024 + t * 4];
  __syncthreads();
  float acc[16];
  #pragma unroll
  for (int j = 0; j < 16; j++) acc[j] = 0.f;
  const float* wp = Wp + (size_t)hseg * 64 * KD + k;
  #pragma unroll 8
  for (int hh = 0; hh < 64; hh++) {
    float w = wp[(size_t)hh * KD];
    const float4* ar = (const float4*)&Asm[hh * 16];
    #pragma unroll
    for (int qq = 0; qq < 4; qq++) {
      float4 a = ar[qq];
      acc[qq*4+0] += w * a.x; acc[qq*4+1] += w * a.y;
      acc[qq*4+2] += w * a.z; acc[qq*4+3] += w * a.w;
    }
  }
  float* o = part + ((size_t)hseg * 1024 + k) * 16;
  #pragma unroll
  for (int qq = 0; qq < 4; qq++) {
    float4 r; r.x = acc[qq*4]; r.y = acc[qq*4+1]; r.z = acc[qq*4+2]; r.w = acc[qq*4+3];
    *(float4*)&o[qq * 4] = r;
  }
}

// ---------- WpAT[r][k] = sum_seg part[seg][k][r]  (bf16 out) ----------
__global__ __launch_bounds__(256) void wpat_reduce(const float* __restrict__ part,
                                                   u16* __restrict__ WpAT) {
  int idx = blockIdx.x * 256 + threadIdx.x;   // 0..16383
  int k = idx & 1023, r = idx >> 10;
  float s = 0.f;
  #pragma unroll
  for (int seg = 0; seg < 16; seg++)
    s += part[((size_t)seg * 1024 + k) * 16 + r];
  WpAT[(size_t)r * KD + k] = f2b(s);
}

// ---------- x -> bf16; LN of own row -> shb[row-1]; row s==0 zeroes shb[batch_last] ----------
__global__ __launch_bounds__(256) void ln_shift(const float* __restrict__ x,
                                                const float* __restrict__ gamma,
                                                const float* __restrict__ beta,
                                                u16* __restrict__ xb,
                                                u16* __restrict__ shb) {
  int row = blockIdx.x;           // 0..16383
  int t = threadIdx.x;
  int s = row & (SEQ - 1);
  const float* xr = x + (size_t)row * KD;
  float4 v = *(const float4*)(xr + t * 4);
  ushort4 o; o.x = f2b(v.x); o.y = f2b(v.y); o.z = f2b(v.z); o.w = f2b(v.w);
  *(ushort4*)(xb + (size_t)row * KD + t * 4) = o;

  if (s == 0) {  // block-uniform: zero the batch's last shifted row, skip LN
    ushort4 z; z.x = 0; z.y = 0; z.z = 0; z.w = 0;
    *(ushort4*)(shb + ((size_t)row + SEQ - 1) * KD + t * 4) = z;
    return;
  }
  float s1 = v.x + v.y + v.z + v.w;
  float s2 = v.x * v.x + v.y * v.y + v.z * v.z + v.w * v.w;
  #pragma unroll
  for (int off = 32; off > 0; off >>= 1) {
    s1 += __shfl_down(s1, off);
    s2 += __shfl_down(s2, off);
  }
  __shared__ float red[8];
  int wave = t >> 6, lane = t & 63;
  if (lane == 0) { red[wave * 2] = s1; red[wave * 2 + 1] = s2; }
  __syncthreads();
  float sum = red[0] + red[2] + red[4] + red[6];
  float ssq = red[1] + red[3] + red[5] + red[7];
  float mu = sum * (1.0f / KD);
  float var = ssq * (1.0f / KD) - mu * mu;
  float rstd = rsqrtf(var + 1e-5f);
  float4 g = *(const float4*)(gamma + t * 4);
  float4 bb = *(const float4*)(beta + t * 4);
  ushort4 so;
  so.x = f2b((v.x - mu) * rstd * g.x + bb.x);
  so.y = f2b((v.y - mu) * rstd * g.y + bb.y);
  so.z = f2b((v.z - mu) * rstd * g.z + bb.z);
  so.w = f2b((v.w - mu) * rstd * g.w + bb.w);
  *(ushort4*)(shb + (size_t)(row - 1) * KD + t * 4) = so;
}

// ---------- out = xb @ Wb^T + (2*xb@Bef^T) @ Aef^T  (fp32 out; mid fused in-loop) ----------
// BK=64, XCD-aware block swizzle, 8-slot XOR LDS swizzle.
// mid = 2*(xb@Bef[chunk]^T) is accumulated per K-step from the already-staged As tile
// (+4 MFMAs/wave/K-step), redistributed through As (reused) for the LoRA K-extension.
__global__ __launch_bounds__(256, 2) void gemm_fused(const u16* __restrict__ A,
                                                     const u16* __restrict__ Bm,
                                                     const u16* __restrict__ Bef,
                                                     const u16* __restrict__ Aef,
                                                     float* __restrict__ C) {
  constexpr int BM = 128, BN = 128, BK = 64, N = HD, Kd = KD;
  __shared__ u16 As[BM * BK];
  __shared__ u16 Bs[BN * BK];
  int tid = threadIdx.x;
  int lane = tid & 63, wave = tid >> 6;
  // XCD swizzle: lb%8 = XCD; give XCD q a contiguous 16-row-band stripe.
  int lb = blockIdx.x + 8 * blockIdx.y;     // gridDim = (8,128)
  int q = lb & 7, t = lb >> 3;              // t: 0..127
  int mb = q * 16 + (t >> 3);
  int nb = t & 7;
  int m0 = mb * 128, n0 = nb * 128;
  int chunk = m0 >> 8;
  int wm = (wave >> 1) * 64, wn = (wave & 1) * 64;
  int wm2 = wave * 32;          // this wave's 32-row mid sub-tile
  int lr = lane & 15;
  int qd = lane >> 4;          // quad 0..3
  int sw = lr & 7;             // row-derived XOR key
  int slot0 = ((qd ^ sw) * 8);             // h=0 k-offset (u16)
  int slot1 = (((4 + qd) ^ sw) * 8);       // h=1
  int rb = qd * 4, cc = lr;    // C-layout row-block / col
  f32x4 acc[4][4] = {};
  f32x4 macc[2] = {};          // mid accumulator (2 m-tiles x 16 r)

  const u16* gbase; u16* lbase;
  if (wave < 2) { gbase = A + (size_t)(m0 + wave * 64) * Kd; lbase = As + wave * 64 * BK; }
  else          { gbase = Bm + (size_t)(n0 + (wave - 2) * 64) * Kd; lbase = Bs + (wave - 2) * 64 * BK; }
  int srow = lane >> 3;                       // 0..7
  int scol = ((lane & 7) ^ srow) * 8;         // swizzled global slot
  const u16* gsrc = gbase + (size_t)srow * Kd + scol;
  const u16* befk = Bef + (size_t)chunk * (RK * KD) + (size_t)lr * Kd + qd * 8;

  for (int k0 = 0; k0 < Kd; k0 += BK) {
    #pragma unroll
    for (int i = 0; i < 8; i++)
      async16(gsrc + (size_t)i * 8 * Kd, lbase + i * 512);
    gsrc += BK;
    __syncthreads();
    s16x8 af[4], bfr[4];
    // h = 0
    #pragma unroll
    for (int i = 0; i < 4; i++) af[i] = *(const s16x8*)(As + (wm + i * 16 + lr) * BK + slot0);
    #pragma unroll
    for (int j = 0; j < 4; j++) bfr[j] = *(const s16x8*)(Bs + (wn + j * 16 + lr) * BK + slot0);
    #pragma unroll
    for (int i = 0; i < 4; i++)
      #pragma unroll
      for (int j = 0; j < 4; j++)
        acc[i][j] = __builtin_amdgcn_mfma_f32_16x16x32_bf16(af[i], bfr[j], acc[i][j], 0, 0, 0);
    // h = 1
    #pragma unroll
    for (int i = 0; i < 4; i++) af[i] = *(const s16x8*)(As + (wm + i * 16 + lr) * BK + slot1);
    #pragma unroll
    for (int j = 0; j < 4; j++) bfr[j] = *(const s16x8*)(Bs + (wn + j * 16 + lr) * BK + slot1);
    #pragma unroll
    for (int i = 0; i < 4; i++)
      #pragma unroll
      for (int j = 0; j < 4; j++)
        acc[i][j] = __builtin_amdgcn_mfma_f32_16x16x32_bf16(af[i], bfr[j], acc[i][j], 0, 0, 0);
    // mid accumulation: macc += As_rows(wm2..wm2+31) @ Bef_k_slice^T  (L2-hot 16B loads)
    {
      s16x8 bf0 = *(const s16x8*)(befk);
      s16x8 bf1 = *(const s16x8*)(befk + 32);
      #pragma unroll
      for (int i2 = 0; i2 < 2; i2++) {
        s16x8 a0 = *(const s16x8*)(As + (wm2 + i2 * 16 + lr) * BK + slot0);
        macc[i2] = __builtin_amdgcn_mfma_f32_16x16x32_bf16(a0, bf0, macc[i2], 0, 0, 0);
        s16x8 a1 = *(const s16x8*)(As + (wm2 + i2 * 16 + lr) * BK + slot1);
        macc[i2] = __builtin_amdgcn_mfma_f32_16x16x32_bf16(a1, bf1, macc[i2], 0, 0, 0);
      }
      befk += BK;
    }
    __syncthreads();
  }

  // Redistribute mid through As (reused as u16[128][16]): C-layout write, A-layout read.
  #pragma unroll
  for (int i2 = 0; i2 < 2; i2++)
    #pragma unroll
    for (int p = 0; p < 4; p++)
      As[(wm2 + i2 * 16 + rb + p) * 16 + cc] = f2b(SCALE_OUT * macc[i2][p]);
  __syncthreads();

  // LoRA K-extension: one zero-padded k-step with mid fragments from LDS.
  {
    const u16* abase = Aef + (size_t)chunk * (HD * RK);
    int klane = lane >> 4;        // only 0,1 carry real k
    s16x8 am2[4], bn2[4];
    #pragma unroll
    for (int i = 0; i < 4; i++) {
      if (klane < 2)
        am2[i] = *(const s16x8*)(As + (wm + i * 16 + lr) * 16 + klane * 8);
      else { s16x8 z = {}; am2[i] = z; }
    }
    #pragma unroll
    for (int j = 0; j < 4; j++) {
      if (klane < 2)
        bn2[j] = *(const s16x8*)(abase + (size_t)(n0 + wn + j * 16 + lr) * RK + klane * 8);
      else { s16x8 z = {}; bn2[j] = z; }
    }
    #pragma unroll
    for (int i = 0; i < 4; i++)
      #pragma unroll
      for (int j = 0; j < 4; j++)
        acc[i][j] = __builtin_amdgcn_mfma_f32_16x16x32_bf16(am2[i], bn2[j], acc[i][j], 0, 0, 0);
  }

  #pragma unroll
  for (int i = 0; i < 4; i++)
    #pragma unroll
    for (int j = 0; j < 4; j++)
      #pragma unroll
      for (int p = 0; p < 4; p++)
        C[(size_t)(m0 + wm + i * 16 + rb + p) * N + (n0 + wn + j * 16 + cc)] = acc[i][j][p];
}

// ---------- rank-16 MFMA: O[M x 16] = X[M x 1024] @ W[16 x 1024]^T ----------
// z=0: pin = xb @ initB^T ; z=1: per = shb @ WpAT^T (= V @ init_A)
__global__ __launch_bounds__(256) void rank16_proj(const u16* __restrict__ xb,
                                                   const u16* __restrict__ shb,
                                                   const u16* __restrict__ iBb,
                                                   const u16* __restrict__ WpAT,
                                                   float* __restrict__ pin,
                                                   float* __restrict__ per) {
  const u16* X; const u16* W; float* O;
  if (blockIdx.z == 0) { X = xb; W = iBb; O = pin; }
  else                 { X = shb; W = WpAT; O = per; }
  int wave = threadIdx.x >> 6, lane = threadIdx.x & 63;
  int m0 = (blockIdx.x * 4 + wave) * 16;
  int lr = lane & 15, lk = (lane >> 4) * 8;
  const u16* xp = X + (size_t)(m0 + lr) * KD + lk;
  const u16* wp = W + (size_t)lr * KD + lk;
  f32x4 acc = {};
  #pragma unroll 4
  for (int k0 = 0; k0 < KD; k0 += 32) {
    s16x8 a = *(const s16x8*)xp;
    s16x8 b = *(const s16x8*)wp;
    acc = __builtin_amdgcn_mfma_f32_16x16x32_bf16(a, b, acc, 0, 0, 0);
    xp += 32; wp += 32;
  }
  int rb = (lane >> 4) * 4, cc = lane & 15;
  #pragma unroll
  for (int p = 0; p < 4; p++)
    O[(size_t)(m0 + rb + p) * RK + cc] = acc[p];
}

// ---------- z=0: G[c][r][k] = sum_cc shb[cc][k]*pin[cc][r]
// ---------- z=1: dB[c][r][k] = sum_cc per[cc][r]*xb[cc][k]
__global__ __launch_bounds__(256) void gk_kernel(const u16* __restrict__ xb,
                                                 const u16* __restrict__ shb,
                                                 const float* __restrict__ pin,
                                                 const float* __restrict__ per,
                                                 float* __restrict__ G,
                                                 float* __restrict__ dB) {
  int tile = blockIdx.x;    // 0..3
  int chunk = blockIdx.y;
  int which = blockIdx.z;
  int t = threadIdx.x;
  __shared__ float P[CH * RK];
  const float* psrc = which ? per : pin;
  for (int i = t; i < 1024; i += 256)
    *(float4*)&P[i * 4] = *(const float4*)&psrc[(size_t)chunk * 4096 + i * 4];
  __syncthreads();
  float acc[16];
  #pragma unroll
  for (int j = 0; j < 16; j++) acc[j] = 0.f;
  int col = tile * 256 + t;
  const u16* src = (which ? xb : shb) + (size_t)chunk * CH * KD + col;
  for (int c = 0; c < 256; c++) {
    float v = b2f(src[(size_t)c * 1024]);
    const float4* pr = (const float4*)&P[c * 16];
    #pragma unroll
    for (int qq = 0; qq < 4; qq++) {
      float4 p = pr[qq];
      acc[qq*4+0] += v * p.x; acc[qq*4+1] += v * p.y;
      acc[qq*4+2] += v * p.z; acc[qq*4+3] += v * p.w;
    }
  }
  float* o = (which ? dB : G) + (size_t)chunk * 16384 + col;
  #pragma unroll
  for (int j = 0; j < 16; j++) o[(size_t)j * 1024] = acc[j];
}

// ---------- exclusive cumsum over chunks, scaled by lr ----------
__global__ __launch_bounds__(256) void cumsum_kernel(const float* __restrict__ G,
                                                     const float* __restrict__ dB,
                                                     u16* __restrict__ rawG,
                                                     float* __restrict__ rawB) {
  int idx = blockIdx.x * 256 + threadIdx.x;  // 0..65535
  int which = idx >> 15;
  int rem = idx & 32767;
  int b = rem >> 14;
  int e = rem & 16383;
  size_t base = (size_t)b * 32 * 16384 + e;
  if (which == 0) {
    float run = 0.f;
    for (int i = 0; i < 32; i++) {
      size_t off = base + (size_t)i * 16384;
      float nv = G[off];
      rawG[off] = f2b(LR_SC * run);
      run += nv;
    }
  } else {
    float run = 0.f;
    for (int i = 0; i < 32; i++) {
      size_t off = base + (size_t)i * 16384;
      float nv = dB[off];
      rawB[off] = LR_SC * run;
      run += nv;
    }
  }
}

// ---------- rawA[c][h][r] = sum_k Wpb[h][k] * rawG[c][r][k]  (fp32 out) ----------
__global__ __launch_bounds__(256) void dagemm(const u16* __restrict__ Wpb,
                                              const u16* __restrict__ rawG,
                                              float* __restrict__ rawA) {
  int wave = threadIdx.x >> 6, lane = threadIdx.x & 63;
  int m0 = (blockIdx.x * 4 + wave) * 16;   // h-tile
  int chunk = blockIdx.y;
  int lr = lane & 15, lk = (lane >> 4) * 8;
  const u16* ap = Wpb + (size_t)(m0 + lr) * KD + lk;
  const u16* bp = rawG + (size_t)chunk * 16384 + (size_t)lr * KD + lk;
  f32x4 acc = {};
  #pragma unroll 4
  for (int k0 = 0; k0 < KD; k0 += 32) {
    s16x8 a = *(const s16x8*)ap;
    s16x8 b = *(const s16x8*)bp;
    acc = __builtin_amdgcn_mfma_f32_16x16x32_bf16(a, b, acc, 0, 0, 0);
    ap += 32; bp += 32;
  }
  int rb = (lane >> 4) * 4, cc = lane & 15;
  #pragma unroll
  for (int p = 0; p < 4; p++)
    rawA[(size_t)chunk * 16384 + (size_t)(m0 + rb + p) * RK + cc] = acc[p];
}

// ---------- joint norm clip + A_eff/B_eff emit (fused; 1024 threads for MLP) ----------
__global__ __launch_bounds__(1024) void coef_eff(const float* __restrict__ initA,
                                                 const float* __restrict__ initB,
                                                 const float* __restrict__ rawA,
                                                 const float* __restrict__ rawB,
                                                 u16* __restrict__ Aef,
                                                 u16* __restrict__ Bef) {
  int chunk = blockIdx.x, t = threadIdx.x;
  const float* a = rawA + (size_t)chunk * 16384;
  const float* b = rawB + (size_t)chunk * 16384;
  float s = 0.f;
  #pragma unroll
  for (int i = t * 4; i < 16384; i += 4096) {
    float4 v = *(const float4*)(a + i);
    s += v.x*v.x + v.y*v.y + v.z*v.z + v.w*v.w;
    float4 w = *(const float4*)(b + i);
    s += w.x*w.x + w.y*w.y + w.z*w.z + w.w*w.w;
  }
  #pragma unroll
  for (int off = 32; off > 0; off >>= 1) s += __shfl_down(s, off);
  __shared__ float red[16];
  int wave = t >> 6, lane = t & 63;
  if (lane == 0) red[wave] = s;
  __syncthreads();
  float tot = 0.f;
  #pragma unroll
  for (int w = 0; w < 16; w++) tot += red[w];
  float cf = fminf(1.0f / (sqrtf(tot) + 1e-6f), 1.0f);
  u16* ao = Aef + (size_t)chunk * 16384;
  u16* bo = Bef + (size_t)chunk * 16384;
  #pragma unroll
  for (int i = t * 4; i < 16384; i += 4096) {
    float4 iv = *(const float4*)(initA + i);
    float4 rv = *(const float4*)(a + i);
    ushort4 r;
    r.x = f2b(iv.x - rv.x * cf); r.y = f2b(iv.y - rv.y * cf);
    r.z = f2b(iv.z - rv.z * cf); r.w = f2b(iv.w - rv.w * cf);
    *(ushort4*)(ao + i) = r;
    float4 iw = *(const float4*)(initB + i);
    float4 rw = *(const float4*)(b + i);
    ushort4 rr;
    rr.x = f2b(iw.x - rw.x * cf); rr.y = f2b(iw.y - rw.y * cf);
    rr.z = f2b(iw.z - rw.z * cf); rr.w = f2b(iw.w - rw.w * cf);
    *(ushort4*)(bo + i) = rr;
  }
}

extern "C" void kernel_launch(void* const* d_in, const int* in_sizes, int n_in,
                              void* d_out, int out_size, void* d_ws, size_t ws_size,
                              hipStream_t stream) {
  (void)in_sizes; (void)n_in; (void)out_size; (void)ws_size;
  const float* x     = (const float*)d_in[0];
  const float* Wb    = (const float*)d_in[1];
  const float* initA = (const float*)d_in[2];
  const float* initB = (const float*)d_in[3];
  const float* gamma = (const float*)d_in[4];
  const float* beta  = (const float*)d_in[5];
  const float* Wp    = (const float*)d_in[6];
  float* out = (float*)d_out;

  char* ws = (char*)d_ws;
  size_t off = 0;
  auto alloc = [&](size_t bytes) -> void* {
    void* p = ws + off;
    off = (off + bytes + 255) & ~(size_t)255;
    return p;
  };
  const size_t ROWS = (size_t)B_SZ * SEQ;  // 16384
  u16* xb    = (u16*)alloc(ROWS * KD * 2);
  u16* shb   = (u16*)alloc(ROWS * KD * 2);
  u16* Wbb   = (u16*)alloc((size_t)HD * KD * 2);
  u16* Wpb   = (u16*)alloc((size_t)HD * KD * 2);
  u16* iBb   = (u16*)alloc((size_t)RK * KD * 2);
  u16* WpAT  = (u16*)alloc((size_t)RK * KD * 2);
  float* wpart = (float*)alloc((size_t)16 * KD * RK * 4);
  float* pin = (float*)alloc((size_t)NCH * CH * RK * 4);
  float* per = (float*)alloc((size_t)NCH * CH * RK * 4);
  float* G   = (float*)alloc((size_t)NCH * 16384 * 4);
  float* dB  = (float*)alloc((size_t)NCH * 16384 * 4);
  u16* rawG  = (u16*)alloc((size_t)NCH * 16384 * 2);
  float* rawB= (float*)alloc((size_t)NCH * 16384 * 4);
  float* rawA= (float*)alloc((size_t)NCH * 16384 * 4);
  u16* Aef   = (u16*)alloc((size_t)NCH * 16384 * 2);
  u16* Bef   = (u16*)alloc((size_t)NCH * 16384 * 2);

  cvt_all<<<2064, 256, 0, stream>>>(Wb, Wp, initB, Wbb, Wpb, iBb);
  wpat_part<<<dim3(4, 16), 256, 0, stream>>>(initA, Wp, wpart);
  wpat_reduce<<<64, 256, 0, stream>>>(wpart, WpAT);
  ln_shift<<<ROWS, 256, 0, stream>>>(x, gamma, beta, xb, shb);
  rank16_proj<<<dim3(256, 1, 2), 256, 0, stream>>>(xb, shb, iBb, WpAT, pin, per);
  gk_kernel<<<dim3(4, NCH, 2), 256, 0, stream>>>(xb, shb, pin, per, G, dB);
  cumsum_kernel<<<256, 256, 0, stream>>>(G, dB, rawG, rawB);
  dagemm<<<dim3(16, NCH), 256, 0, stream>>>(Wpb, rawG, rawA);
  coef_eff<<<NCH, 1024, 0, stream>>>(initA, initB, rawA, rawB, Aef, Bef);
  gemm_fused<<<dim3(8, 128), 256, 0, stream>>>(xb, Wbb, Bef, Aef, out);
}